// Round 3
// baseline (9272.177 us; speedup 1.0000x reference)
//
#include <hip/hip_runtime.h>
#include <hip/hip_bf16.h>

// ---------------------------------------------------------------------------
// MPNN_block_seperate — full fp32 data path (bf16 intermediates measurably
// break the softmax-logit precision budget: round-2 absmax 0.156 vs thr 0.075).
// All three conv blocks are two-pass (stats pass -> fused conv+BN+ReLU+pool
// apply pass) so raw conv outputs are never materialized.  Block1->Block2 is
// batch-chunked (2 chunks) so peak workspace = P1chunk(67.6MB)+P2(34.6MB)
// ~= 102 MB, under the proven-safe 111 MB.  If ws_size >= 170 MB we use one
// chunk and skip the conv1 recompute (ws_size is constant across calls, so
// the branch is graph-capture safe).
// ---------------------------------------------------------------------------

#define TPB 256
#define CO_T 64
#define L_T  64
#define CIC  16

// stats block offsets (floats)
#define RAW1 0
#define FIN1 512
#define RAW2 1024
#define FIN2 1280
#define RAW3 1536
#define FIN3 2048
#define RAWG 2560
#define ST_FLOATS 2688

// ---------------- conv1 stats: reads x[b][s][n][d] directly ----------------
__global__ __launch_bounds__(TPB) void conv1_stats_k(const float* __restrict__ x,
                                                     const float* __restrict__ w,
                                                     float* __restrict__ raw)
{
    __shared__ float s_in[CIC * 68];
    __shared__ float s_w[CO_T * 49];
    int bn = blockIdx.z;
    int bq = bn >> 6, n = bn & 63;
    int co0 = blockIdx.y * CO_T;
    int l0  = blockIdx.x * L_T;
    int tid = threadIdx.x;
    int lt = tid & 15, cg = tid >> 4, ll = lt * 4;
    const float* xb = x + (size_t)bq * 1048576 + (size_t)n * 64;

    float acc[4][4] = {};
    for (int ci0 = 0; ci0 < 64; ci0 += CIC) {
        for (int idx = tid; idx < 66 * 16; idx += TPB) {
            int jj = idx >> 4, c = idx & 15;
            int gl = l0 - 1 + jj;
            float v = 0.f;
            if (gl >= 0 && gl < 256) v = xb[(size_t)gl * 4096 + ci0 + c];
            s_in[c * 68 + jj] = v;
        }
        for (int idx = tid; idx < CO_T * 48; idx += TPB) {
            int c = idx / 48, r = idx - c * 48;
            s_w[c * 49 + r] = w[((size_t)(co0 + c) * 64 + ci0) * 3 + r];
        }
        __syncthreads();
#pragma unroll
        for (int cc = 0; cc < CIC; cc++) {
            float4 v4 = *(const float4*)&s_in[cc * 68 + ll];
            float iv[6] = { v4.x, v4.y, v4.z, v4.w,
                            s_in[cc * 68 + ll + 4], s_in[cc * 68 + ll + 5] };
#pragma unroll
            for (int j = 0; j < 4; j++) {
                const float* wp = &s_w[(cg * 4 + j) * 49 + cc * 3];
                float w0 = wp[0], w1 = wp[1], w2 = wp[2];
#pragma unroll
                for (int i = 0; i < 4; i++)
                    acc[j][i] += w0 * iv[i] + w1 * iv[i + 1] + w2 * iv[i + 2];
            }
        }
        __syncthreads();
    }
#pragma unroll
    for (int j = 0; j < 4; j++) {
        float s1 = acc[j][0] + acc[j][1] + acc[j][2] + acc[j][3];
        float s2 = acc[j][0] * acc[j][0] + acc[j][1] * acc[j][1] +
                   acc[j][2] * acc[j][2] + acc[j][3] * acc[j][3];
#pragma unroll
        for (int m = 1; m < 16; m <<= 1) { s1 += __shfl_xor(s1, m); s2 += __shfl_xor(s2, m); }
        if (lt == 0) {
            int co = co0 + cg * 4 + j;
            atomicAdd(&raw[co], s1);
            atomicAdd(&raw[256 + co], s2);
        }
    }
}

// ---------------- conv1 + BN + ReLU + maxpool -> P1 chunk (fp32) ------------
__global__ __launch_bounds__(TPB) void conv1_pool_k(const float* __restrict__ x,
                                                    const float* __restrict__ w,
                                                    const float* __restrict__ fin,
                                                    const float* __restrict__ g,
                                                    const float* __restrict__ bt,
                                                    float* __restrict__ out,
                                                    int bn0)
{
    __shared__ float s_in[CIC * 68];   // col jj = in[l0-2+jj], jj in [0,67)
    __shared__ float s_w[CO_T * 49];
    __shared__ float s_z[64 * 66];     // col0 = z[l0-1], cols 1..64 = z[l0..l0+63]
    int bl = blockIdx.z;
    int bn = bn0 + bl;
    int bq = bn >> 6, n = bn & 63;
    int co0 = blockIdx.y * CO_T;
    int l0  = blockIdx.x * L_T;
    int tid = threadIdx.x;
    int lt = tid & 15, cg = tid >> 4, ll = lt * 4;
    const float* xb = x + (size_t)bq * 1048576 + (size_t)n * 64;

    float acc[4][4] = {};
    float accE[4] = {};
    for (int ci0 = 0; ci0 < 64; ci0 += CIC) {
        for (int idx = tid; idx < 67 * 16; idx += TPB) {
            int jj = idx >> 4, c = idx & 15;
            int gl = l0 - 2 + jj;
            float v = 0.f;
            if (gl >= 0 && gl < 256) v = xb[(size_t)gl * 4096 + ci0 + c];
            s_in[c * 68 + jj] = v;
        }
        for (int idx = tid; idx < CO_T * 48; idx += TPB) {
            int c = idx / 48, r = idx - c * 48;
            s_w[c * 49 + r] = w[((size_t)(co0 + c) * 64 + ci0) * 3 + r];
        }
        __syncthreads();
#pragma unroll
        for (int cc = 0; cc < CIC; cc++) {
            float4 a4 = *(const float4*)&s_in[cc * 68 + ll];
            float4 b4 = *(const float4*)&s_in[cc * 68 + ll + 4];
            float iv[8] = { a4.x, a4.y, a4.z, a4.w, b4.x, b4.y, b4.z, b4.w };
#pragma unroll
            for (int j = 0; j < 4; j++) {
                const float* wp = &s_w[(cg * 4 + j) * 49 + cc * 3];
                float w0 = wp[0], w1 = wp[1], w2 = wp[2];
                accE[j] += w0 * iv[0] + w1 * iv[1] + w2 * iv[2];
#pragma unroll
                for (int i = 0; i < 4; i++)
                    acc[j][i] += w0 * iv[i + 1] + w1 * iv[i + 2] + w2 * iv[i + 3];
            }
        }
        __syncthreads();
    }
#pragma unroll
    for (int j = 0; j < 4; j++) {
        int co = co0 + cg * 4 + j;
        float scale = g[co] * fin[256 + co];
        float shift = bt[co] - fin[co] * scale;
        int row = (cg * 4 + j) * 66;
#pragma unroll
        for (int i = 0; i < 4; i++) {
            float z = acc[j][i] * scale + shift;
            s_z[row + ll + i + 1] = z > 0.f ? z : 0.f;
        }
        if (lt == 0) {
            float zE = 0.f;
            if (l0 > 0) { zE = accE[j] * scale + shift; zE = zE > 0.f ? zE : 0.f; }
            s_z[row] = zE;
        }
    }
    __syncthreads();
    float* ob = out + ((size_t)bl * 256 + co0) * 129;
    int jbase = l0 >> 1;
    for (int idx = tid; idx < 2048; idx += TPB) {
        int col = idx >> 5, jl = idx & 31;
        float v = fmaxf(s_z[col * 66 + 2 * jl], s_z[col * 66 + 2 * jl + 1]);
        ob[(size_t)col * 129 + jbase + jl] = v;
    }
    if (l0 == 192 && tid < 64)   // window j=128 uses only z[255]
        ob[(size_t)tid * 129 + 128] = s_z[tid * 66 + 64];
}

// ---------------- generic fp32 conv stats (no output store) ----------------
__global__ __launch_bounds__(TPB) void conv_stats_k(const float* __restrict__ in,
                                                    const float* __restrict__ w,
                                                    float* __restrict__ raw,
                                                    int CI, int CO, int Lin, int pad)
{
    __shared__ float s_in[CIC * 68];
    __shared__ float s_w[CO_T * 49];
    int b   = blockIdx.z;
    int co0 = blockIdx.y * CO_T;
    int l0  = blockIdx.x * L_T;
    int tid = threadIdx.x;
    int lt = tid & 15, cg = tid >> 4, ll = lt * 4;
    const float* inb = in + (size_t)b * CI * Lin;

    float acc[4][4] = {};
    for (int ci0 = 0; ci0 < CI; ci0 += CIC) {
        for (int idx = tid; idx < CIC * 66; idx += TPB) {
            int c = idx / 66, jj = idx - c * 66;
            int gl = l0 - pad + jj;
            float v = 0.f;
            if (gl >= 0 && gl < Lin) v = inb[(size_t)(ci0 + c) * Lin + gl];
            s_in[c * 68 + jj] = v;
        }
        for (int idx = tid; idx < CO_T * 48; idx += TPB) {
            int c = idx / 48, r = idx - c * 48;
            s_w[c * 49 + r] = w[((size_t)(co0 + c) * CI + ci0) * 3 + r];
        }
        __syncthreads();
#pragma unroll
        for (int cc = 0; cc < CIC; cc++) {
            float4 v4 = *(const float4*)&s_in[cc * 68 + ll];
            float iv[6] = { v4.x, v4.y, v4.z, v4.w,
                            s_in[cc * 68 + ll + 4], s_in[cc * 68 + ll + 5] };
#pragma unroll
            for (int j = 0; j < 4; j++) {
                const float* wp = &s_w[(cg * 4 + j) * 49 + cc * 3];
                float w0 = wp[0], w1 = wp[1], w2 = wp[2];
#pragma unroll
                for (int i = 0; i < 4; i++)
                    acc[j][i] += w0 * iv[i] + w1 * iv[i + 1] + w2 * iv[i + 2];
            }
        }
        __syncthreads();
    }
    // positions beyond Lout read only padded zeros -> contribute exact 0
#pragma unroll
    for (int j = 0; j < 4; j++) {
        float s1 = acc[j][0] + acc[j][1] + acc[j][2] + acc[j][3];
        float s2 = acc[j][0] * acc[j][0] + acc[j][1] * acc[j][1] +
                   acc[j][2] * acc[j][2] + acc[j][3] * acc[j][3];
#pragma unroll
        for (int m = 1; m < 16; m <<= 1) { s1 += __shfl_xor(s1, m); s2 += __shfl_xor(s2, m); }
        if (lt == 0) {
            int co = co0 + cg * 4 + j;
            atomicAdd(&raw[co], s1);
            atomicAdd(&raw[CO + co], s2);
        }
    }
}

// ------------- generic fp32 conv + BN + ReLU + maxpool(2,2,pad1) -----------
// EPI=0: out[((bn0+bz)*CO + co)*Lp + j]   (P2 layout)
// EPI=1: fold to spa[((b*72+tc)*64+n)*128+f],  linear=c*36+j (block-3 layout)
template<int EPI>
__global__ __launch_bounds__(TPB) void conv_pool_k(const float* __restrict__ in,
                                                   const float* __restrict__ w,
                                                   const float* __restrict__ fin,
                                                   const float* __restrict__ g,
                                                   const float* __restrict__ bt,
                                                   float* __restrict__ out,
                                                   int CI, int CO, int Lin, int pad,
                                                   int Lvalid, int Lp, int bn0)
{
    __shared__ float s_in[CIC * 68];   // col jj = in[l0-pad-1+jj], jj in [0,67)
    __shared__ float s_w[CO_T * 49];
    __shared__ float s_z[64 * 66];
    int bz  = blockIdx.z;
    int co0 = blockIdx.y * CO_T;
    int l0  = blockIdx.x * L_T;
    int tid = threadIdx.x;
    int lt = tid & 15, cg = tid >> 4, ll = lt * 4;
    const float* inb = in + (size_t)bz * CI * Lin;

    float acc[4][4] = {};
    float accE[4] = {};
    for (int ci0 = 0; ci0 < CI; ci0 += CIC) {
        for (int idx = tid; idx < CIC * 67; idx += TPB) {
            int c = idx / 67, jj = idx - c * 67;
            int gl = l0 - pad - 1 + jj;
            float v = 0.f;
            if (gl >= 0 && gl < Lin) v = inb[(size_t)(ci0 + c) * Lin + gl];
            s_in[c * 68 + jj] = v;
        }
        for (int idx = tid; idx < CO_T * 48; idx += TPB) {
            int c = idx / 48, r = idx - c * 48;
            s_w[c * 49 + r] = w[((size_t)(co0 + c) * CI + ci0) * 3 + r];
        }
        __syncthreads();
#pragma unroll
        for (int cc = 0; cc < CIC; cc++) {
            float4 a4 = *(const float4*)&s_in[cc * 68 + ll];
            float4 b4 = *(const float4*)&s_in[cc * 68 + ll + 4];
            float iv[8] = { a4.x, a4.y, a4.z, a4.w, b4.x, b4.y, b4.z, b4.w };
#pragma unroll
            for (int j = 0; j < 4; j++) {
                const float* wp = &s_w[(cg * 4 + j) * 49 + cc * 3];
                float w0 = wp[0], w1 = wp[1], w2 = wp[2];
                accE[j] += w0 * iv[0] + w1 * iv[1] + w2 * iv[2];
#pragma unroll
                for (int i = 0; i < 4; i++)
                    acc[j][i] += w0 * iv[i + 1] + w1 * iv[i + 2] + w2 * iv[i + 3];
            }
        }
        __syncthreads();
    }
#pragma unroll
    for (int j = 0; j < 4; j++) {
        int co = co0 + cg * 4 + j;
        float scale = g[co] * fin[CO + co];
        float shift = bt[co] - fin[co] * scale;
        int row = (cg * 4 + j) * 66;
#pragma unroll
        for (int i = 0; i < 4; i++) {
            float z = acc[j][i] * scale + shift;
            s_z[row + ll + i + 1] = z > 0.f ? z : 0.f;
        }
        if (lt == 0) {
            float zE = 0.f;
            if (l0 > 0) { zE = accE[j] * scale + shift; zE = zE > 0.f ? zE : 0.f; }
            s_z[row] = zE;
        }
    }
    __syncthreads();
    int jbase = l0 >> 1;
    for (int idx = tid; idx < 2048; idx += TPB) {
        int col = idx >> 5, jl = idx & 31;
        int j = jbase + jl;
        if (j >= Lp) continue;
        float v1 = s_z[col * 66 + 2 * jl];                           // z[2j-1] (col0 = edge)
        float v2 = (2 * j < Lvalid) ? s_z[col * 66 + 2 * jl + 1] : 0.f; // z[2j]
        float v = fmaxf(v1, v2);
        if (EPI == 0) {
            out[((size_t)(bn0 + bz) * CO + co0 + col) * (size_t)Lp + j] = v;
        } else {
            int c = co0 + col;
            int linear = c * 36 + j;
            int tc = linear >> 7, f = linear & 127;
            int bq = bz >> 6, n = bz & 63;
            out[(((size_t)bq * 72 + tc) * 64 + n) * 128 + f] = v;
        }
    }
}

__global__ __launch_bounds__(TPB) void bn_fin_k(const float* __restrict__ raw,
                                                float* __restrict__ fin, int C, float invN)
{
    int c = threadIdx.x + blockIdx.x * TPB;
    if (c < C) {
        float m = raw[c] * invN;
        float v = raw[C + c] * invN - m * m;
        fin[c] = m;
        fin[C + c] = rsqrtf(v + 1e-5f);
    }
}

// ---------------- nf = spa @ map_w^T + map_b ----------------
__global__ __launch_bounds__(TPB) void gemm_nf_k(const float* __restrict__ A,
                                                 const float* __restrict__ W,
                                                 const float* __restrict__ bias,
                                                 float* __restrict__ out)
{
    __shared__ float s_a[64 * 33];
    __shared__ float s_w[128 * 33];
    int r0 = blockIdx.x * 64;
    int tid = threadIdx.x;
    int rg = tid >> 4, cgc = tid & 15;
    float acc[4][8];
#pragma unroll
    for (int i = 0; i < 8; i++) {
        float bv = bias[cgc + 16 * i];
#pragma unroll
        for (int j = 0; j < 4; j++) acc[j][i] = bv;
    }
    for (int k0 = 0; k0 < 128; k0 += 32) {
        for (int idx = tid; idx < 64 * 32; idx += TPB) {
            int r = idx >> 5, kk = idx & 31;
            s_a[r * 33 + kk] = A[(size_t)(r0 + r) * 128 + k0 + kk];
        }
        for (int idx = tid; idx < 128 * 32; idx += TPB) {
            int f = idx >> 5, kk = idx & 31;
            s_w[f * 33 + kk] = W[(size_t)f * 128 + k0 + kk];
        }
        __syncthreads();
#pragma unroll
        for (int kk = 0; kk < 32; kk++) {
            float av[4];
#pragma unroll
            for (int j = 0; j < 4; j++) av[j] = s_a[(rg * 4 + j) * 33 + kk];
#pragma unroll
            for (int i = 0; i < 8; i++) {
                float wv = s_w[(cgc + 16 * i) * 33 + kk];
#pragma unroll
                for (int j = 0; j < 4; j++) acc[j][i] += av[j] * wv;
            }
        }
        __syncthreads();
    }
#pragma unroll
    for (int j = 0; j < 4; j++) {
        size_t row = (size_t)(r0 + rg * 4 + j) * 128;
#pragma unroll
        for (int i = 0; i < 8; i++) out[row + cgc + 16 * i] = acc[j][i];
    }
}

// ---------------- graph kernel (adj/softmax/G/out) per b' slice ----------------
__global__ __launch_bounds__(TPB) void graph_k(const float* __restrict__ nf,
                                               const float* __restrict__ theta_w,
                                               const float* __restrict__ theta_b,
                                               float* __restrict__ gout)
{
    __shared__ float s_nfT[128 * 66];  // [f][n] stride 66; aliased as s_G [m][o] later
    __shared__ float s_adj[64 * 64];
    __shared__ float s_red[256];
    __shared__ float s_rmax[64];
    __shared__ float s_rsum[64];
    float* s_G = s_nfT;

    int bp = blockIdx.x;
    int tid = threadIdx.x;
    const float* nfb = nf + (size_t)bp * 64 * 128;

    for (int idx = tid; idx < 64 * 128; idx += TPB) {
        int n = idx >> 7, f = idx & 127;
        s_nfT[f * 66 + n] = nfb[idx];
    }
    __syncthreads();

    int mg = tid & 15, ng = tid >> 4;
    {
        float a[4][4] = {};
#pragma unroll 4
        for (int f = 0; f < 128; f++) {
            float nv[4], mv[4];
#pragma unroll
            for (int j = 0; j < 4; j++) nv[j] = s_nfT[f * 66 + ng * 4 + j];
#pragma unroll
            for (int i = 0; i < 4; i++) mv[i] = s_nfT[f * 66 + mg * 4 + i];
#pragma unroll
            for (int j = 0; j < 4; j++)
#pragma unroll
                for (int i = 0; i < 4; i++) a[j][i] += nv[j] * mv[i];
        }
#pragma unroll
        for (int j = 0; j < 4; j++)
#pragma unroll
            for (int i = 0; i < 4; i++) {
                int n = ng * 4 + j, m = mg * 4 + i;
                float v = a[j][i];
                if (n == m) v -= 1e8f;
                v = v > 0.f ? v : 0.01f * v;
                s_adj[n * 64 + m] = v;
            }
    }
    __syncthreads();
    {
        int n = tid >> 2, q = tid & 3;
        float mx = -3.0e38f;
        for (int m = q * 16; m < q * 16 + 16; m++) mx = fmaxf(mx, s_adj[n * 64 + m]);
        s_red[n * 4 + q] = mx;
    }
    __syncthreads();
    if (tid < 64)
        s_rmax[tid] = fmaxf(fmaxf(s_red[tid * 4], s_red[tid * 4 + 1]),
                            fmaxf(s_red[tid * 4 + 2], s_red[tid * 4 + 3]));
    __syncthreads();
    {
        int n = tid >> 2, q = tid & 3;
        float mx = s_rmax[n];
        float sm = 0.f;
        for (int m = q * 16; m < q * 16 + 16; m++) {
            float e = __expf(s_adj[n * 64 + m] - mx);
            s_adj[n * 64 + m] = e;
            sm += e;
        }
        s_red[n * 4 + q] = sm;
    }
    __syncthreads();
    if (tid < 64)
        s_rsum[tid] = 1.0f / (s_red[tid * 4] + s_red[tid * 4 + 1] +
                              s_red[tid * 4 + 2] + s_red[tid * 4 + 3]);
    __syncthreads();
    {
        int n = tid >> 2, q = tid & 3;
        float inv = s_rsum[n];
        for (int m = q * 16; m < q * 16 + 16; m++)
            s_adj[n * 64 + m] = s_adj[n * 64 + m] * inv + ((n == m) ? 1.f : 0.f);
    }
    __syncthreads();
    {
        float ga[4][4] = {};
#pragma unroll 4
        for (int f = 0; f < 128; f++) {
            float mv[4], tv[4];
#pragma unroll
            for (int j = 0; j < 4; j++) mv[j] = s_nfT[f * 66 + ng * 4 + j];
#pragma unroll
            for (int i = 0; i < 4; i++) tv[i] = theta_w[(size_t)(mg + 16 * i) * 128 + f];
#pragma unroll
            for (int j = 0; j < 4; j++)
#pragma unroll
                for (int i = 0; i < 4; i++) ga[j][i] += mv[j] * tv[i];
        }
        __syncthreads();   // finish all s_nfT reads before aliasing as s_G
#pragma unroll
        for (int j = 0; j < 4; j++)
#pragma unroll
            for (int i = 0; i < 4; i++)
                s_G[(ng * 4 + j) * 66 + mg + 16 * i] = ga[j][i];
    }
    __syncthreads();
    {
        float oacc[4][4];
#pragma unroll
        for (int i = 0; i < 4; i++) {
            float bv = theta_b[mg + 16 * i];
#pragma unroll
            for (int j = 0; j < 4; j++) oacc[j][i] = bv;
        }
#pragma unroll 4
        for (int m = 0; m < 64; m++) {
            float av[4], gv[4];
#pragma unroll
            for (int j = 0; j < 4; j++) av[j] = s_adj[(ng * 4 + j) * 64 + m];
#pragma unroll
            for (int i = 0; i < 4; i++) gv[i] = s_G[m * 66 + mg + 16 * i];
#pragma unroll
            for (int j = 0; j < 4; j++)
#pragma unroll
                for (int i = 0; i < 4; i++) oacc[j][i] += av[j] * gv[i];
        }
        float* gb = gout + (size_t)bp * 64 * 64;
#pragma unroll
        for (int j = 0; j < 4; j++)
#pragma unroll
            for (int i = 0; i < 4; i++)
                gb[(size_t)(ng * 4 + j) * 64 + mg + 16 * i] = oacc[j][i];
    }
}

// ---------------- stats over gout [73728][64] per feature o ----------------
__global__ __launch_bounds__(TPB) void stat_inner_k(const float* __restrict__ y,
                                                    float* __restrict__ raw,
                                                    int rows_per_block)
{
    int tid = threadIdx.x;
    int o = tid & 63, rr = tid >> 6;
    long r0 = (long)blockIdx.x * rows_per_block;
    float s1 = 0.f, s2 = 0.f;
    for (int r = rr; r < rows_per_block; r += 4) {
        float v = y[(r0 + r) * 64 + o];
        s1 += v; s2 += v * v;
    }
    __shared__ float b1[TPB], b2[TPB];
    b1[tid] = s1; b2[tid] = s2; __syncthreads();
    if (tid < 128) { b1[tid] += b1[tid + 128]; b2[tid] += b2[tid + 128]; }
    __syncthreads();
    if (tid < 64) {
        atomicAdd(&raw[o], b1[tid] + b1[tid + 64]);
        atomicAdd(&raw[64 + o], b2[tid] + b2[tid + 64]);
    }
}

// ---------------- final BN + leaky + pair mean -> [16][36][64][64] ----------------
__global__ __launch_bounds__(TPB) void final_k(const float* __restrict__ gout,
                                               const float* __restrict__ raw,
                                               const float* __restrict__ g,
                                               const float* __restrict__ b,
                                               float* __restrict__ out)
{
    long idx = (long)blockIdx.x * TPB + threadIdx.x;
    if (idx >= 2359296L) return;
    int o = (int)(idx & 63);
    long t = idx >> 6;
    int n = (int)(t & 63);
    long t2 = t >> 6;
    long wd = t2 % 36;
    long bb = t2 / 36;
    const float invN = 1.0f / 73728.0f;
    float m = raw[o] * invN;
    float var = raw[64 + o] * invN - m * m;
    float scale = g[o] * rsqrtf(var + 1e-5f);
    float shift = b[o] - m * scale;
    long bp = bb * 72 + wd * 2;
    float v0 = gout[(bp * 64 + n) * 64 + o] * scale + shift;
    float v1 = gout[((bp + 1) * 64 + n) * 64 + o] * scale + shift;
    v0 = v0 > 0.f ? v0 : 0.01f * v0;
    v1 = v1 > 0.f ? v1 : 0.01f * v1;
    out[idx] = 0.5f * (v0 + v1);
}

// ---------------------------------------------------------------------------
extern "C" void kernel_launch(void* const* d_in, const int* in_sizes, int n_in,
                              void* d_out, int out_size, void* d_ws, size_t ws_size,
                              hipStream_t stream)
{
    (void)in_sizes; (void)n_in; (void)out_size;
    const float* x    = (const float*)d_in[0];
    const float* c1w  = (const float*)d_in[1];
    const float* g1   = (const float*)d_in[2];
    const float* b1   = (const float*)d_in[3];
    const float* c2w  = (const float*)d_in[4];
    const float* g2   = (const float*)d_in[5];
    const float* b2   = (const float*)d_in[6];
    const float* c3w  = (const float*)d_in[7];
    const float* g3   = (const float*)d_in[8];
    const float* b3   = (const float*)d_in[9];
    const float* mapw = (const float*)d_in[10];
    const float* mapb = (const float*)d_in[11];
    const float* thw  = (const float*)d_in[12];
    const float* thb  = (const float*)d_in[13];
    const float* bng  = (const float*)d_in[14];
    const float* bnb  = (const float*)d_in[15];
    float* out = (float*)d_out;
    float* ws  = (float*)d_ws;

    // ws_size is constant across calls -> identical launch sequence every call.
    const size_t MONO_BYTES = (size_t)(33816576 + 8650752 + ST_FLOATS) * 4;
    int nch = (ws_size >= MONO_BYTES) ? 1 : 2;
    int chunk = 1024 / nch;
    size_t P1SZ = (size_t)chunk * 256 * 129;

    float* P1c  = ws;                       // [chunk][256][129]
    float* P2   = ws + P1SZ;                // [1024][128][66]
    float* SPA  = ws;                       // [1152][64][128]  (P1c dead)
    float* NF   = ws + 9437184;             // [1152][64][128]  (P2 dead)
    float* GOUT = ws;                       // [1152][64][64]   (SPA dead)
    float* ST   = ws + P1SZ + 8650752;

    hipMemsetAsync((void*)ST, 0, ST_FLOATS * sizeof(float), stream);

    // ---- block 1 stats ----
    conv1_stats_k<<<dim3(4, 4, 1024), TPB, 0, stream>>>(x, c1w, ST + RAW1);
    bn_fin_k<<<1, TPB, 0, stream>>>(ST + RAW1, ST + FIN1, 256, 1.0f / 262144.0f);

    // ---- block1 apply + block2 stats, per chunk ----
    for (int c = 0; c < nch; c++) {
        conv1_pool_k<<<dim3(4, 4, chunk), TPB, 0, stream>>>(x, c1w, ST + FIN1, g1, b1,
                                                            P1c, c * chunk);
        conv_stats_k<<<dim3(3, 2, chunk), TPB, 0, stream>>>(P1c, c2w, ST + RAW2,
                                                            256, 128, 129, 2);
    }
    bn_fin_k<<<1, TPB, 0, stream>>>(ST + RAW2, ST + FIN2, 128, 1.0f / 134144.0f);

    // ---- block2 apply (recompute P1 chunk if chunked) ----
    for (int c = 0; c < nch; c++) {
        if (nch > 1)
            conv1_pool_k<<<dim3(4, 4, chunk), TPB, 0, stream>>>(x, c1w, ST + FIN1, g1, b1,
                                                                P1c, c * chunk);
        conv_pool_k<0><<<dim3(3, 2, chunk), TPB, 0, stream>>>(P1c, c2w, ST + FIN2, g2, b2,
                                                              P2, 256, 128, 129, 2,
                                                              131, 66, c * chunk);
    }

    // ---- block 3 ----
    conv_stats_k<<<dim3(2, 4, 1024), TPB, 0, stream>>>(P2, c3w, ST + RAW3,
                                                       128, 256, 66, 3);
    bn_fin_k<<<1, TPB, 0, stream>>>(ST + RAW3, ST + FIN3, 256, 1.0f / 71680.0f);
    conv_pool_k<1><<<dim3(2, 4, 1024), TPB, 0, stream>>>(P2, c3w, ST + FIN3, g3, b3,
                                                         SPA, 128, 256, 66, 3,
                                                         70, 36, 0);

    // ---- graph stage ----
    gemm_nf_k<<<1152, TPB, 0, stream>>>(SPA, mapw, mapb, NF);
    graph_k<<<1152, TPB, 0, stream>>>(NF, thw, thb, GOUT);
    stat_inner_k<<<288, TPB, 0, stream>>>(GOUT, ST + RAWG, 256);
    final_k<<<9216, TPB, 0, stream>>>(GOUT, ST + RAWG, bng, bnb, out);
}